// Round 10
// baseline (13454.903 us; speedup 1.0000x reference)
//
#include <hip/hip_runtime.h>
#include <hip/hip_cooperative_groups.h>
#include <math.h>

namespace cg = cooperative_groups;

// ---------------------------------------------------------------------------
// Hierarchical bi-GRU (char bi-GRU -> word bi-GRU -> FC head), fp32.
//
// r10: char level + stages = r8 configuration verbatim (64x64 gemm_k loop —
// proven 2.3ms, many small blocks for latency hiding). Word level = NEW
// cooperative weight-stationary kernel: 512 blocks (16 row-groups x 32
// col-groups, 2 blocks/CU), h/rh staged in LDS, weights read as wave-broadcast
// slices (each weight column read by 16 blocks/step instead of 256),
// 2 grid.sync() per step via hipLaunchCooperativeKernel.
//
//   gates = sigmoid(x@Wg_x + h@Wg_h + bg)      (x-part precomputed)
//   c     = tanh  (x@Wc_x + (r*h)@Wc_h + bc)
//   h'    = mask ? u*h + (1-u)*c : h
// ---------------------------------------------------------------------------

#define TILE 64
#define BKK 16

enum AMode { A_PLAIN = 0, A_CHARSTATE = 1, A_RH = 2, A_GATHER = 3 };
enum EMode { E_BIAS = 0, E_GATE_CHAR = 1, E_CAND_CHAR = 2, E_XW = 3 };

struct GemmArgs {
  int M, N, K;
  const float* A; int lda;
  const float* G; int ldg;
  const int*   arows;
  const float* B;
  const float* bias;
  const float* XT; int ldxt;
  const int*   seqs;
  const int*   lens;
  int t, T;
  const int*   cidx;
  const float* Hin;
  float* Cout; int ldc;
};

__device__ __forceinline__ float sigmoidf_(float x) { return 1.0f / (1.0f + expf(-x)); }

template<int AM, int EM>
__global__ __launch_bounds__(256) void gemm_k(GemmArgs p) {
  __shared__ float As[BKK][TILE];
  __shared__ float Bs[BKK][TILE];
  const int tid = threadIdx.x;
  const int tx = tid & 15, ty = tid >> 4;
  const int m0 = blockIdx.y * TILE, n0 = blockIdx.x * TILE;
  const int la_r = tid >> 2, la_k = (tid & 3) << 2;
  const int lb_k = tid >> 4, lb_n = (tid & 15) << 2;

  float acc[4][4] = {};
  int arow = 0;
  if constexpr (AM == A_GATHER) arow = p.arows[m0 + la_r];

  for (int k0 = 0; k0 < p.K; k0 += BKK) {
    float4 av;
    const int m = m0 + la_r;
    const int k = k0 + la_k;
    if constexpr (AM == A_PLAIN) {
      av = *reinterpret_cast<const float4*>(p.A + (size_t)m * p.lda + k);
    } else if constexpr (AM == A_CHARSTATE) {
      const float* ap = (k < 512) ? (p.A + (size_t)m * 512 + k)
                                  : (p.A + (size_t)(2048 + m) * 512 + (k - 512));
      av = *reinterpret_cast<const float4*>(ap);
    } else if constexpr (AM == A_RH) {
      float4 g = *reinterpret_cast<const float4*>(p.G + (size_t)m * p.ldg + k);
      float4 h = *reinterpret_cast<const float4*>(p.A + (size_t)m * p.lda + k);
      av = make_float4(g.x * h.x, g.y * h.y, g.z * h.z, g.w * h.w);
    } else { // A_GATHER
      av = *reinterpret_cast<const float4*>(p.A + (size_t)arow * p.lda + k);
    }
    As[la_k + 0][la_r] = av.x;
    As[la_k + 1][la_r] = av.y;
    As[la_k + 2][la_r] = av.z;
    As[la_k + 3][la_r] = av.w;
    float4 bv = *reinterpret_cast<const float4*>(p.B + (size_t)(k0 + lb_k) * p.N + n0 + lb_n);
    *reinterpret_cast<float4*>(&Bs[lb_k][lb_n]) = bv;
    __syncthreads();
#pragma unroll
    for (int kk = 0; kk < BKK; ++kk) {
      float4 a = *reinterpret_cast<const float4*>(&As[kk][ty << 2]);
      float4 b = *reinterpret_cast<const float4*>(&Bs[kk][tx << 2]);
      acc[0][0] += a.x * b.x; acc[0][1] += a.x * b.y; acc[0][2] += a.x * b.z; acc[0][3] += a.x * b.w;
      acc[1][0] += a.y * b.x; acc[1][1] += a.y * b.y; acc[1][2] += a.y * b.z; acc[1][3] += a.y * b.w;
      acc[2][0] += a.z * b.x; acc[2][1] += a.z * b.y; acc[2][2] += a.z * b.z; acc[2][3] += a.z * b.w;
      acc[3][0] += a.w * b.x; acc[3][1] += a.w * b.y; acc[3][2] += a.w * b.z; acc[3][3] += a.w * b.w;
    }
    __syncthreads();
  }

  const int rbase = m0 + (ty << 2);
  const int cbase = n0 + (tx << 2);
#pragma unroll
  for (int i = 0; i < 4; ++i) {
    const int row = rbase + i;
    if constexpr (EM == E_BIAS) {
#pragma unroll
      for (int j = 0; j < 4; ++j) {
        const int col = cbase + j;
        p.Cout[(size_t)row * p.ldc + col] = acc[i][j] + p.bias[col];
      }
    } else if constexpr (EM == E_GATE_CHAR || EM == E_CAND_CHAR) {
      const int us = row & 2047;
      const bool dir = row >= 2048;
      const int len = p.lens[us];
      int pos = dir ? (len - 1 - p.t) : p.t;
      pos = pos < 0 ? 0 : (pos > p.T - 1 ? p.T - 1 : pos);
      const int ch = p.seqs[us * p.T + pos];
      const float* xrow = p.XT + (size_t)ch * p.ldxt;
      const bool mask = p.t < len;
#pragma unroll
      for (int j = 0; j < 4; ++j) {
        const int col = cbase + j;
        if constexpr (EM == E_GATE_CHAR) {
          p.Cout[(size_t)row * p.ldc + col] = sigmoidf_(acc[i][j] + xrow[col]);
        } else {
          const float cv = tanhf(acc[i][j] + xrow[col]);
          const float u  = p.G[(size_t)row * p.ldg + 512 + col];
          const float h  = p.Hin[(size_t)row * 512 + col];
          p.Cout[(size_t)row * p.ldc + col] = mask ? (u * h + (1.0f - u) * cv) : h;
        }
      }
    } else { // E_XW
      const int cs = p.cidx[row];
      const float* xrow = p.XT + (size_t)cs * p.ldxt;
#pragma unroll
      for (int j = 0; j < 4; ++j) {
        const int col = cbase + j;
        p.Cout[(size_t)row * p.ldc + col] = acc[i][j] + xrow[col];
      }
    }
  }
}

// ---------------------------------------------------------------------------
// Cooperative word bi-GRU: 512 blocks x 256 threads, 16 row-groups (32 rows)
// x 32 col-groups. Phase1: gate cols [j*32, j*32+32); Phase2: cand cols
// [j*16, j*16+16). h/rh rows staged in 64KB dynamic LDS; weight reads are
// 128B wave-broadcast slices. 2 grid syncs per step.
// Rows 0..255 = fw (batch b=row), 256..511 = bw (b=row-256).
// ---------------------------------------------------------------------------
template<int TT>
__global__ __launch_bounds__(256, 2) void gru_coop(
    const float* __restrict__ Whg,   // [512][1024] h-part gate weights
    const float* __restrict__ Whc,   // [512][512]  h-part cand weights
    const float* __restrict__ Xg,    // [256*TT][1024] gate x-part (bias folded)
    const float* __restrict__ Xc,    // [256*TT][512]  cand x-part
    const int*   __restrict__ lens,  // [256]
    float* __restrict__ h_g,         // [512][512] zero-init; final = word states
    float* __restrict__ rh_g,        // [512][512]
    float* __restrict__ u_g)         // [512][512]
{
  extern __shared__ float stg[];     // 32 rows x 512 = 64KB
  const int bid = blockIdx.x;
  const int ig  = bid >> 5;          // row-group 0..15
  const int jg  = bid & 31;          // col-group 0..31
  const int r0  = ig * 32;
  const int tid = threadIdx.x;

  // phase-1 mapping: 8 row-quads x 32 cols
  const int rq1 = tid >> 5;                 // 0..7
  const int c1  = jg * 32 + (tid & 31);     // [0,1024)
  // phase-2 mapping: 16 row-pairs x 16 cols
  const int rq2 = tid >> 4;                 // 0..15
  const int c2  = jg * 16 + (tid & 15);     // [0,512)

  int len1[4]; int b1_[4]; bool bw1[4];
#pragma unroll
  for (int q = 0; q < 4; ++q) {
    const int r = r0 + rq1 * 4 + q;
    const bool bw = r >= 256; const int b = bw ? r - 256 : r;
    bw1[q] = bw; b1_[q] = b; len1[q] = lens[b];
  }
  int len2[2]; int b2_[2]; bool bw2[2];
#pragma unroll
  for (int q = 0; q < 2; ++q) {
    const int r = r0 + rq2 * 2 + q;
    const bool bw = r >= 256; const int b = bw ? r - 256 : r;
    bw2[q] = bw; b2_[q] = b; len2[q] = lens[b];
  }

  cg::grid_group grid = cg::this_grid();

  for (int t = 0; t < TT; ++t) {
    // ---- stage h[r0..r0+32) into LDS ----
    for (int idx = tid; idx < 32 * 128; idx += 256) {
      const int r = idx >> 7, kk = (idx & 127) << 2;
      *reinterpret_cast<float4*>(&stg[r * 512 + kk]) =
          *reinterpret_cast<const float4*>(&h_g[(size_t)(r0 + r) * 512 + kk]);
    }
    __syncthreads();

    // ---- phase 1: gates ----
    float acc[4] = {0.f, 0.f, 0.f, 0.f};
#pragma unroll 4
    for (int k = 0; k < 512; k += 4) {
      const float w0 = Whg[(size_t)(k + 0) * 1024 + c1];
      const float w1 = Whg[(size_t)(k + 1) * 1024 + c1];
      const float w2 = Whg[(size_t)(k + 2) * 1024 + c1];
      const float w3 = Whg[(size_t)(k + 3) * 1024 + c1];
#pragma unroll
      for (int q = 0; q < 4; ++q) {
        const float4 hv = *reinterpret_cast<const float4*>(&stg[(rq1 * 4 + q) * 512 + k]);
        acc[q] += hv.x * w0 + hv.y * w1 + hv.z * w2 + hv.w * w3;
      }
    }
#pragma unroll
    for (int q = 0; q < 4; ++q) {
      const int r = r0 + rq1 * 4 + q;
      const int L = len1[q];
      int pos = bw1[q] ? (L - 1 - t) : t;
      pos = pos < 0 ? 0 : (pos > TT - 1 ? TT - 1 : pos);
      const size_t xr = (size_t)(b1_[q] * TT + pos);
      const float g = sigmoidf_(acc[q] + Xg[xr * 1024 + c1]);
      if (c1 < 512) rh_g[(size_t)r * 512 + c1] = g * stg[(rq1 * 4 + q) * 512 + c1];
      else          u_g [(size_t)r * 512 + (c1 - 512)] = g;
    }
    grid.sync();

    // ---- stage rh[r0..r0+32) into LDS ----
    for (int idx = tid; idx < 32 * 128; idx += 256) {
      const int r = idx >> 7, kk = (idx & 127) << 2;
      *reinterpret_cast<float4*>(&stg[r * 512 + kk]) =
          *reinterpret_cast<const float4*>(&rh_g[(size_t)(r0 + r) * 512 + kk]);
    }
    __syncthreads();

    // ---- phase 2: cand + h update ----
    float acc2[2] = {0.f, 0.f};
#pragma unroll 4
    for (int k = 0; k < 512; k += 4) {
      const float w0 = Whc[(size_t)(k + 0) * 512 + c2];
      const float w1 = Whc[(size_t)(k + 1) * 512 + c2];
      const float w2 = Whc[(size_t)(k + 2) * 512 + c2];
      const float w3 = Whc[(size_t)(k + 3) * 512 + c2];
#pragma unroll
      for (int q = 0; q < 2; ++q) {
        const float4 rv = *reinterpret_cast<const float4*>(&stg[(rq2 * 2 + q) * 512 + k]);
        acc2[q] += rv.x * w0 + rv.y * w1 + rv.z * w2 + rv.w * w3;
      }
    }
#pragma unroll
    for (int q = 0; q < 2; ++q) {
      const int r = r0 + rq2 * 2 + q;
      const int L = len2[q];
      if (t < L) {
        int pos = bw2[q] ? (L - 1 - t) : t;
        pos = pos < 0 ? 0 : (pos > TT - 1 ? TT - 1 : pos);
        const size_t xr = (size_t)(b2_[q] * TT + pos);
        const float cv = tanhf(acc2[q] + Xc[xr * 512 + c2]);
        const float u  = u_g[(size_t)r * 512 + c2];
        const float ho = h_g[(size_t)r * 512 + c2];
        h_g[(size_t)r * 512 + c2] = u * ho + (1.0f - u) * cv;
      }
    }
    grid.sync();
  }
}

// FC head: states = concat(fw,bw) [256,1024] -> leaky_relu(@W1+b1,0.2) -> @W2+b2
__global__ __launch_bounds__(64) void head_k(const float* __restrict__ Hw,
                                             const float* __restrict__ W1,
                                             const float* __restrict__ b1,
                                             const float* __restrict__ W2,
                                             const float* __restrict__ b2,
                                             float* __restrict__ out) {
  __shared__ float s[1024];
  __shared__ float hid[64];
  const int b = blockIdx.x;
  const int tid = threadIdx.x;
  for (int k = tid; k < 512; k += 64) {
    s[k]       = Hw[(size_t)b * 512 + k];
    s[512 + k] = Hw[(size_t)(256 + b) * 512 + k];
  }
  __syncthreads();
  float acc = b1[tid];
  for (int k = 0; k < 1024; ++k) acc += s[k] * W1[k * 64 + tid];
  acc = acc > 0.0f ? acc : 0.2f * acc;
  hid[tid] = acc;
  __syncthreads();
  if (tid < 2) {
    float a = b2[tid];
    for (int k = 0; k < 64; ++k) a += hid[k] * W2[k * 2 + tid];
    out[b * 2 + tid] = a;
  }
}

extern "C" void kernel_launch(void* const* d_in, const int* in_sizes, int n_in,
                              void* d_out, int out_size, void* d_ws, size_t ws_size,
                              hipStream_t stream) {
  const int*   charseqs      = (const int*)d_in[0];
  const int*   charseq_lens  = (const int*)d_in[1];
  const int*   charseq_ids   = (const int*)d_in[2];
  const int*   word_ids      = (const int*)d_in[3];
  const int*   sentence_lens = (const int*)d_in[4];
  const float* char_emb      = (const float*)d_in[5];
  const float* word_emb      = (const float*)d_in[6];
  const float* Wg_c          = (const float*)d_in[7];
  const float* bg_c          = (const float*)d_in[8];
  const float* Wc_c          = (const float*)d_in[9];
  const float* bc_c          = (const float*)d_in[10];
  const float* Wg_w          = (const float*)d_in[11];
  const float* bg_w          = (const float*)d_in[12];
  const float* Wc_w          = (const float*)d_in[13];
  const float* bc_w          = (const float*)d_in[14];
  const float* W1            = (const float*)d_in[15];
  const float* b1            = (const float*)d_in[16];
  const float* W2            = (const float*)d_in[17];
  const float* b2            = (const float*)d_in[18];
  float* out = (float*)d_out;

  float* ws = (float*)d_ws;
  size_t off = 0;
  auto alloc = [&](size_t n) { float* p = ws + off; off += n; return p; };
  float* XTABg = alloc(256 * 1024);
  float* XTABc = alloc(256 * 512);
  float* HcA   = alloc((size_t)4096 * 512);
  float* HcB   = alloc((size_t)4096 * 512);
  float* Gc    = alloc((size_t)4096 * 1024);
  float* CTABg = alloc((size_t)2048 * 1024);
  float* CTABc = alloc((size_t)2048 * 512);
  float* XWg   = alloc((size_t)16384 * 1024);
  float* XWc   = alloc((size_t)16384 * 512);
  float* Hw    = alloc(512 * 512);   // word h state (zero-init; final output)
  float* RHg   = alloc(512 * 512);   // word rh scratch
  float* Ug    = alloc(512 * 512);   // word u scratch

  hipMemsetAsync(HcA, 0, (size_t)4096 * 512 * sizeof(float), stream);
  hipMemsetAsync(Hw,  0, (size_t)512 * 512 * sizeof(float), stream);

  // --- Stage A: char x-part tables ---
  {
    GemmArgs a{}; a.M = 256; a.N = 1024; a.K = 128;
    a.A = char_emb; a.lda = 128; a.B = Wg_c; a.bias = bg_c; a.Cout = XTABg; a.ldc = 1024;
    gemm_k<A_PLAIN, E_BIAS><<<dim3(1024 / TILE, 256 / TILE), 256, 0, stream>>>(a);
    GemmArgs c{}; c.M = 256; c.N = 512; c.K = 128;
    c.A = char_emb; c.lda = 128; c.B = Wc_c; c.bias = bc_c; c.Cout = XTABc; c.ldc = 512;
    gemm_k<A_PLAIN, E_BIAS><<<dim3(512 / TILE, 256 / TILE), 256, 0, stream>>>(c);
  }

  // --- Stage B: char bi-GRU GEMM loop (64-tile, r8 config) ---
  float* hcur = HcA; float* hnext = HcB;
  for (int t = 0; t < 16; ++t) {
    GemmArgs g{}; g.M = 4096; g.N = 1024; g.K = 512;
    g.A = hcur; g.lda = 512; g.B = Wg_c + 128 * 1024;
    g.XT = XTABg; g.ldxt = 1024; g.seqs = charseqs; g.lens = charseq_lens; g.t = t; g.T = 16;
    g.Cout = Gc; g.ldc = 1024;
    gemm_k<A_PLAIN, E_GATE_CHAR><<<dim3(1024 / TILE, 4096 / TILE), 256, 0, stream>>>(g);

    GemmArgs c{}; c.M = 4096; c.N = 512; c.K = 512;
    c.A = hcur; c.lda = 512; c.G = Gc; c.ldg = 1024; c.B = Wc_c + 128 * 512;
    c.XT = XTABc; c.ldxt = 512; c.seqs = charseqs; c.lens = charseq_lens; c.t = t; c.T = 16;
    c.Hin = hcur; c.Cout = hnext; c.ldc = 512;
    gemm_k<A_RH, E_CAND_CHAR><<<dim3(512 / TILE, 4096 / TILE), 256, 0, stream>>>(c);

    float* tmp = hcur; hcur = hnext; hnext = tmp;
  }
  // after 16 steps hcur == HcA

  // --- Stage C: per-wordform x-part ---
  {
    GemmArgs a{}; a.M = 2048; a.N = 1024; a.K = 1024;
    a.A = hcur; a.B = Wg_w; a.bias = bg_w; a.Cout = CTABg; a.ldc = 1024;
    gemm_k<A_CHARSTATE, E_BIAS><<<dim3(1024 / TILE, 2048 / TILE), 256, 0, stream>>>(a);
    GemmArgs c{}; c.M = 2048; c.N = 512; c.K = 1024;
    c.A = hcur; c.B = Wc_w; c.bias = bc_w; c.Cout = CTABc; c.ldc = 512;
    gemm_k<A_CHARSTATE, E_BIAS><<<dim3(512 / TILE, 2048 / TILE), 256, 0, stream>>>(c);
  }

  // --- Stage D: word-emb x-part + CTAB gather ---
  {
    GemmArgs a{}; a.M = 16384; a.N = 1024; a.K = 256;
    a.A = word_emb; a.lda = 256; a.arows = word_ids; a.B = Wg_w + (size_t)1024 * 1024;
    a.XT = CTABg; a.ldxt = 1024; a.cidx = charseq_ids; a.Cout = XWg; a.ldc = 1024;
    gemm_k<A_GATHER, E_XW><<<dim3(1024 / TILE, 16384 / TILE), 256, 0, stream>>>(a);
    GemmArgs c{}; c.M = 16384; c.N = 512; c.K = 256;
    c.A = word_emb; c.lda = 256; c.arows = word_ids; c.B = Wc_w + (size_t)1024 * 512;
    c.XT = CTABc; c.ldxt = 512; c.cidx = charseq_ids; c.Cout = XWc; c.ldc = 512;
    gemm_k<A_GATHER, E_XW><<<dim3(512 / TILE, 16384 / TILE), 256, 0, stream>>>(c);
  }

  // --- Stage E: cooperative word bi-GRU ---
  {
    const float* Whg_p = Wg_w + (size_t)1280 * 1024;
    const float* Whc_p = Wc_w + (size_t)1280 * 512;
    const float* Xg_p  = XWg;
    const float* Xc_p  = XWc;
    const int*   lens_p = sentence_lens;
    float* h_p  = Hw;
    float* rh_p = RHg;
    float* u_p  = Ug;
    void* kargs[] = {(void*)&Whg_p, (void*)&Whc_p, (void*)&Xg_p, (void*)&Xc_p,
                     (void*)&lens_p, (void*)&h_p, (void*)&rh_p, (void*)&u_p};
    hipLaunchCooperativeKernel(reinterpret_cast<void*>(gru_coop<64>),
                               dim3(512), dim3(256), kargs,
                               32 * 512 * sizeof(float), stream);
  }

  // --- Stage F: FC head ---
  head_k<<<256, 64, 0, stream>>>(Hw, W1, b1, W2, b2, out);
}

// Round 11
// 5225.538 us; speedup vs baseline: 2.5748x; 2.5748x over previous
//
#include <hip/hip_runtime.h>
#include <math.h>

// ---------------------------------------------------------------------------
// Hierarchical bi-GRU (char bi-GRU -> word bi-GRU -> FC head), fp32.
//
// r11 = r8 (best, 4853us) + word fused kernel widened to 512 threads:
// same R=2 / 256 blocks / weights read once per block-step (traffic law
// unchanged), but 8 waves/block = 2 waves/SIMD (was 1) -> 2x latency hiding.
//
//   gates = sigmoid(x@Wg_x + h@Wg_h + bg)      (x-part precomputed)
//   c     = tanh  (x@Wc_x + (r*h)@Wc_h + bc)
//   h'    = mask ? u*h + (1-u)*c : h
// ---------------------------------------------------------------------------

#define TILE 64
#define BKK 16

enum AMode { A_PLAIN = 0, A_CHARSTATE = 1, A_RH = 2, A_GATHER = 3 };
enum EMode { E_BIAS = 0, E_GATE_CHAR = 1, E_CAND_CHAR = 2, E_XW = 3 };

struct GemmArgs {
  int M, N, K;
  const float* A; int lda;
  const float* G; int ldg;
  const int*   arows;
  const float* B;
  const float* bias;
  const float* XT; int ldxt;
  const int*   seqs;
  const int*   lens;
  int t, T;
  const int*   cidx;
  const float* Hin;
  float* Cout; int ldc;
};

__device__ __forceinline__ float sigmoidf_(float x) { return 1.0f / (1.0f + expf(-x)); }

template<int AM, int EM>
__global__ __launch_bounds__(256) void gemm_k(GemmArgs p) {
  __shared__ float As[BKK][TILE];
  __shared__ float Bs[BKK][TILE];
  const int tid = threadIdx.x;
  const int tx = tid & 15, ty = tid >> 4;
  const int m0 = blockIdx.y * TILE, n0 = blockIdx.x * TILE;
  const int la_r = tid >> 2, la_k = (tid & 3) << 2;
  const int lb_k = tid >> 4, lb_n = (tid & 15) << 2;

  float acc[4][4] = {};
  int arow = 0;
  if constexpr (AM == A_GATHER) arow = p.arows[m0 + la_r];

  for (int k0 = 0; k0 < p.K; k0 += BKK) {
    float4 av;
    const int m = m0 + la_r;
    const int k = k0 + la_k;
    if constexpr (AM == A_PLAIN) {
      av = *reinterpret_cast<const float4*>(p.A + (size_t)m * p.lda + k);
    } else if constexpr (AM == A_CHARSTATE) {
      const float* ap = (k < 512) ? (p.A + (size_t)m * 512 + k)
                                  : (p.A + (size_t)(2048 + m) * 512 + (k - 512));
      av = *reinterpret_cast<const float4*>(ap);
    } else if constexpr (AM == A_RH) {
      float4 g = *reinterpret_cast<const float4*>(p.G + (size_t)m * p.ldg + k);
      float4 h = *reinterpret_cast<const float4*>(p.A + (size_t)m * p.lda + k);
      av = make_float4(g.x * h.x, g.y * h.y, g.z * h.z, g.w * h.w);
    } else { // A_GATHER
      av = *reinterpret_cast<const float4*>(p.A + (size_t)arow * p.lda + k);
    }
    As[la_k + 0][la_r] = av.x;
    As[la_k + 1][la_r] = av.y;
    As[la_k + 2][la_r] = av.z;
    As[la_k + 3][la_r] = av.w;
    float4 bv = *reinterpret_cast<const float4*>(p.B + (size_t)(k0 + lb_k) * p.N + n0 + lb_n);
    *reinterpret_cast<float4*>(&Bs[lb_k][lb_n]) = bv;
    __syncthreads();
#pragma unroll
    for (int kk = 0; kk < BKK; ++kk) {
      float4 a = *reinterpret_cast<const float4*>(&As[kk][ty << 2]);
      float4 b = *reinterpret_cast<const float4*>(&Bs[kk][tx << 2]);
      acc[0][0] += a.x * b.x; acc[0][1] += a.x * b.y; acc[0][2] += a.x * b.z; acc[0][3] += a.x * b.w;
      acc[1][0] += a.y * b.x; acc[1][1] += a.y * b.y; acc[1][2] += a.y * b.z; acc[1][3] += a.y * b.w;
      acc[2][0] += a.z * b.x; acc[2][1] += a.z * b.y; acc[2][2] += a.z * b.z; acc[2][3] += a.z * b.w;
      acc[3][0] += a.w * b.x; acc[3][1] += a.w * b.y; acc[3][2] += a.w * b.z; acc[3][3] += a.w * b.w;
    }
    __syncthreads();
  }

  const int rbase = m0 + (ty << 2);
  const int cbase = n0 + (tx << 2);
#pragma unroll
  for (int i = 0; i < 4; ++i) {
    const int row = rbase + i;
    if constexpr (EM == E_BIAS) {
#pragma unroll
      for (int j = 0; j < 4; ++j) {
        const int col = cbase + j;
        p.Cout[(size_t)row * p.ldc + col] = acc[i][j] + p.bias[col];
      }
    } else if constexpr (EM == E_GATE_CHAR || EM == E_CAND_CHAR) {
      const int us = row & 2047;
      const bool dir = row >= 2048;
      const int len = p.lens[us];
      int pos = dir ? (len - 1 - p.t) : p.t;
      pos = pos < 0 ? 0 : (pos > p.T - 1 ? p.T - 1 : pos);
      const int ch = p.seqs[us * p.T + pos];
      const float* xrow = p.XT + (size_t)ch * p.ldxt;
      const bool mask = p.t < len;
#pragma unroll
      for (int j = 0; j < 4; ++j) {
        const int col = cbase + j;
        if constexpr (EM == E_GATE_CHAR) {
          p.Cout[(size_t)row * p.ldc + col] = sigmoidf_(acc[i][j] + xrow[col]);
        } else {
          const float cv = tanhf(acc[i][j] + xrow[col]);
          const float u  = p.G[(size_t)row * p.ldg + 512 + col];
          const float h  = p.Hin[(size_t)row * 512 + col];
          p.Cout[(size_t)row * p.ldc + col] = mask ? (u * h + (1.0f - u) * cv) : h;
        }
      }
    } else { // E_XW
      const int cs = p.cidx[row];
      const float* xrow = p.XT + (size_t)cs * p.ldxt;
#pragma unroll
      for (int j = 0; j < 4; ++j) {
        const int col = cbase + j;
        p.Cout[(size_t)row * p.ldc + col] = acc[i][j] + xrow[col];
      }
    }
  }
}

// ---------------------------------------------------------------------------
// Fused persistent word GRU, 512 threads: R=2 rows/block, 256 blocks.
// Phase 1: thread owns gate cols {2t,2t+1} for BOTH rows (float2 weight load,
// Whg read once per block-step). Phase 2: thread owns cand col {t}.
// 8 waves/block = 2 waves/SIMD.
// Rows: [0,NU) = forward, [NU,2NU) = backward (dir uniform per block).
// ---------------------------------------------------------------------------
template<int R, int NU, int TT>
__global__ __launch_bounds__(512) void gru_word(
    const float* __restrict__ Whg,   // [512,1024]
    const float* __restrict__ Whc,   // [512,512]
    const float* __restrict__ Xg,    // [NU*TT,1024] (bias folded)
    const float* __restrict__ Xc,    // [NU*TT,512]
    const int*   __restrict__ lens,  // [NU]
    float* __restrict__ Hout)        // [2*NU, 512]
{
  __shared__ float h_s [R][512];
  __shared__ float rh_s[R][512];
  __shared__ float u_s [R][512];
  __shared__ int   xog_s[R];
  __shared__ int   xoc_s[R];
  __shared__ int   msk_s[R];

  const int tid  = threadIdx.x;
  const int row0 = blockIdx.x * R;
  const int us0  = row0 & (NU - 1);
  const bool bw  = row0 >= NU;

  for (int i = tid; i < R * 512; i += 512) h_s[i >> 9][i & 511] = 0.0f;
  int mylen = 0;
  if (tid < R) mylen = lens[us0 + tid];
  __syncthreads();

  const int cg = tid << 1;   // phase-1 gate col pair [0,1024)
  const int cc = tid;        // phase-2 cand col [0,512)

  for (int t = 0; t < TT; ++t) {
    if (tid < R) {
      int pos = bw ? (mylen - 1 - t) : t;
      pos = pos < 0 ? 0 : (pos > TT - 1 ? TT - 1 : pos);
      const int xr = (us0 + tid) * TT + pos;
      xog_s[tid] = xr * 1024;
      xoc_s[tid] = xr * 512;
      msk_s[tid] = (t < mylen) ? 1 : 0;
    }
    __syncthreads();

    // ---- phase 1: gates = sigmoid(h @ Whg + Xg); rh / u -> LDS ----
    float2 acc[R];
#pragma unroll
    for (int r = 0; r < R; ++r) acc[r] = make_float2(0.f, 0.f);
#pragma unroll 8
    for (int k = 0; k < 512; ++k) {
      const float2 w = *reinterpret_cast<const float2*>(Whg + (size_t)k * 1024 + cg);
#pragma unroll
      for (int r = 0; r < R; ++r) {
        const float hv = h_s[r][k];
        acc[r].x += hv * w.x; acc[r].y += hv * w.y;
      }
    }
#pragma unroll
    for (int r = 0; r < R; ++r) {
      const float2 x = *reinterpret_cast<const float2*>(Xg + xog_s[r] + cg);
      float2 g;
      g.x = sigmoidf_(acc[r].x + x.x);
      g.y = sigmoidf_(acc[r].y + x.y);
      if (cg < 512) {        // r-gate cols -> rh = r * h
        rh_s[r][cg + 0] = g.x * h_s[r][cg + 0];
        rh_s[r][cg + 1] = g.y * h_s[r][cg + 1];
      } else {               // u-gate cols
        u_s[r][cg - 512 + 0] = g.x;
        u_s[r][cg - 512 + 1] = g.y;
      }
    }
    __syncthreads();

    // ---- phase 2: c = tanh(rh @ Whc + Xc); h' = mask ? u*h+(1-u)*c : h ----
    float acc2[R];
#pragma unroll
    for (int r = 0; r < R; ++r) acc2[r] = 0.f;
#pragma unroll 8
    for (int k = 0; k < 512; ++k) {
      const float w = Whc[(size_t)k * 512 + cc];
#pragma unroll
      for (int r = 0; r < R; ++r) acc2[r] += rh_s[r][k] * w;
    }
#pragma unroll
    for (int r = 0; r < R; ++r) {
      const float cv = tanhf(acc2[r] + Xc[xoc_s[r] + cc]);
      if (msk_s[r]) {
        const float u = u_s[r][cc];
        const float h = h_s[r][cc];
        h_s[r][cc] = u * h + (1.0f - u) * cv;
      }
    }
    __syncthreads();
  }

  for (int i = tid; i < R * 512; i += 512)
    Hout[(size_t)(row0 + (i >> 9)) * 512 + (i & 511)] = h_s[i >> 9][i & 511];
}

// FC head: states = concat(fw,bw) [256,1024] -> leaky_relu(@W1+b1,0.2) -> @W2+b2
__global__ __launch_bounds__(64) void head_k(const float* __restrict__ Hw,
                                             const float* __restrict__ W1,
                                             const float* __restrict__ b1,
                                             const float* __restrict__ W2,
                                             const float* __restrict__ b2,
                                             float* __restrict__ out) {
  __shared__ float s[1024];
  __shared__ float hid[64];
  const int b = blockIdx.x;
  const int tid = threadIdx.x;
  for (int k = tid; k < 512; k += 64) {
    s[k]       = Hw[(size_t)b * 512 + k];
    s[512 + k] = Hw[(size_t)(256 + b) * 512 + k];
  }
  __syncthreads();
  float acc = b1[tid];
  for (int k = 0; k < 1024; ++k) acc += s[k] * W1[k * 64 + tid];
  acc = acc > 0.0f ? acc : 0.2f * acc;
  hid[tid] = acc;
  __syncthreads();
  if (tid < 2) {
    float a = b2[tid];
    for (int k = 0; k < 64; ++k) a += hid[k] * W2[k * 2 + tid];
    out[b * 2 + tid] = a;
  }
}

extern "C" void kernel_launch(void* const* d_in, const int* in_sizes, int n_in,
                              void* d_out, int out_size, void* d_ws, size_t ws_size,
                              hipStream_t stream) {
  const int*   charseqs      = (const int*)d_in[0];
  const int*   charseq_lens  = (const int*)d_in[1];
  const int*   charseq_ids   = (const int*)d_in[2];
  const int*   word_ids      = (const int*)d_in[3];
  const int*   sentence_lens = (const int*)d_in[4];
  const float* char_emb      = (const float*)d_in[5];
  const float* word_emb      = (const float*)d_in[6];
  const float* Wg_c          = (const float*)d_in[7];
  const float* bg_c          = (const float*)d_in[8];
  const float* Wc_c          = (const float*)d_in[9];
  const float* bc_c          = (const float*)d_in[10];
  const float* Wg_w          = (const float*)d_in[11];
  const float* bg_w          = (const float*)d_in[12];
  const float* Wc_w          = (const float*)d_in[13];
  const float* bc_w          = (const float*)d_in[14];
  const float* W1            = (const float*)d_in[15];
  const float* b1            = (const float*)d_in[16];
  const float* W2            = (const float*)d_in[17];
  const float* b2            = (const float*)d_in[18];
  float* out = (float*)d_out;

  float* ws = (float*)d_ws;
  size_t off = 0;
  auto alloc = [&](size_t n) { float* p = ws + off; off += n; return p; };
  float* XTABg = alloc(256 * 1024);
  float* XTABc = alloc(256 * 512);
  float* HcA   = alloc((size_t)4096 * 512);
  float* HcB   = alloc((size_t)4096 * 512);
  float* Gc    = alloc((size_t)4096 * 1024);
  float* CTABg = alloc((size_t)2048 * 1024);
  float* CTABc = alloc((size_t)2048 * 512);
  float* XWg   = alloc((size_t)16384 * 1024);
  float* XWc   = alloc((size_t)16384 * 512);
  float* Hw    = alloc(512 * 512);

  hipMemsetAsync(HcA, 0, (size_t)4096 * 512 * sizeof(float), stream);

  // --- Stage A: char x-part tables ---
  {
    GemmArgs a{}; a.M = 256; a.N = 1024; a.K = 128;
    a.A = char_emb; a.lda = 128; a.B = Wg_c; a.bias = bg_c; a.Cout = XTABg; a.ldc = 1024;
    gemm_k<A_PLAIN, E_BIAS><<<dim3(1024 / TILE, 256 / TILE), 256, 0, stream>>>(a);
    GemmArgs c{}; c.M = 256; c.N = 512; c.K = 128;
    c.A = char_emb; c.lda = 128; c.B = Wc_c; c.bias = bc_c; c.Cout = XTABc; c.ldc = 512;
    gemm_k<A_PLAIN, E_BIAS><<<dim3(512 / TILE, 256 / TILE), 256, 0, stream>>>(c);
  }

  // --- Stage B: char bi-GRU GEMM loop (64-tile, r8 config) ---
  float* hcur = HcA; float* hnext = HcB;
  for (int t = 0; t < 16; ++t) {
    GemmArgs g{}; g.M = 4096; g.N = 1024; g.K = 512;
    g.A = hcur; g.lda = 512; g.B = Wg_c + 128 * 1024;
    g.XT = XTABg; g.ldxt = 1024; g.seqs = charseqs; g.lens = charseq_lens; g.t = t; g.T = 16;
    g.Cout = Gc; g.ldc = 1024;
    gemm_k<A_PLAIN, E_GATE_CHAR><<<dim3(1024 / TILE, 4096 / TILE), 256, 0, stream>>>(g);

    GemmArgs c{}; c.M = 4096; c.N = 512; c.K = 512;
    c.A = hcur; c.lda = 512; c.G = Gc; c.ldg = 1024; c.B = Wc_c + 128 * 512;
    c.XT = XTABc; c.ldxt = 512; c.seqs = charseqs; c.lens = charseq_lens; c.t = t; c.T = 16;
    c.Hin = hcur; c.Cout = hnext; c.ldc = 512;
    gemm_k<A_RH, E_CAND_CHAR><<<dim3(512 / TILE, 4096 / TILE), 256, 0, stream>>>(c);

    float* tmp = hcur; hcur = hnext; hnext = tmp;
  }
  // after 16 steps hcur == HcA

  // --- Stage C: per-wordform x-part ---
  {
    GemmArgs a{}; a.M = 2048; a.N = 1024; a.K = 1024;
    a.A = hcur; a.B = Wg_w; a.bias = bg_w; a.Cout = CTABg; a.ldc = 1024;
    gemm_k<A_CHARSTATE, E_BIAS><<<dim3(1024 / TILE, 2048 / TILE), 256, 0, stream>>>(a);
    GemmArgs c{}; c.M = 2048; c.N = 512; c.K = 1024;
    c.A = hcur; c.B = Wc_w; c.bias = bc_w; c.Cout = CTABc; c.ldc = 512;
    gemm_k<A_CHARSTATE, E_BIAS><<<dim3(512 / TILE, 2048 / TILE), 256, 0, stream>>>(c);
  }

  // --- Stage D: word-emb x-part + CTAB gather ---
  {
    GemmArgs a{}; a.M = 16384; a.N = 1024; a.K = 256;
    a.A = word_emb; a.lda = 256; a.arows = word_ids; a.B = Wg_w + (size_t)1024 * 1024;
    a.XT = CTABg; a.ldxt = 1024; a.cidx = charseq_ids; a.Cout = XWg; a.ldc = 1024;
    gemm_k<A_GATHER, E_XW><<<dim3(1024 / TILE, 16384 / TILE), 256, 0, stream>>>(a);
    GemmArgs c{}; c.M = 16384; c.N = 512; c.K = 256;
    c.A = word_emb; c.lda = 256; c.arows = word_ids; c.B = Wc_w + (size_t)1024 * 512;
    c.XT = CTABc; c.ldxt = 512; c.cidx = charseq_ids; c.Cout = XWc; c.ldc = 512;
    gemm_k<A_GATHER, E_XW><<<dim3(512 / TILE, 16384 / TILE), 256, 0, stream>>>(c);
  }

  // --- Stage E: fused word bi-GRU (R=2, 256 blocks x 512 threads) ---
  gru_word<2, 256, 64><<<256, 512, 0, stream>>>(
      Wg_w + (size_t)1280 * 1024, Wc_w + (size_t)1280 * 512, XWg, XWc,
      sentence_lens, Hw);

  // --- Stage F: FC head ---
  head_k<<<256, 64, 0, stream>>>(Hw, W1, b1, W2, b2, out);
}

// Round 12
// 4684.480 us; speedup vs baseline: 2.8722x; 1.1155x over previous
//
#include <hip/hip_runtime.h>
#include <math.h>

// ---------------------------------------------------------------------------
// Hierarchical bi-GRU (char bi-GRU -> word bi-GRU -> FC head), fp32.
//
// r12 = r8 (best, 4853us) with the word-level weight stream cut in half:
// recurrent word weights (Whg 2MB, Whc 1MB) pre-converted to bf16 (RNE) once;
// h/state/gates/x-tables stay fp32. Word kernel: R=2, 256 blocks x 256
// threads (r8 structure), inner loops k-step-4 with float4 LDS h-reads and
// 8B/lane bf16 weight loads. Per-block L2 stream 3MB -> 1.5MB per step
// (per-CU pull-rate floor 21.8us -> 10.9us). Char level all-fp32 unchanged.
//
//   gates = sigmoid(x@Wg_x + h@Wg_h + bg)      (x-part precomputed)
//   c     = tanh  (x@Wc_x + (r*h)@Wc_h + bc)
//   h'    = mask ? u*h + (1-u)*c : h
// ---------------------------------------------------------------------------

#define TILE 64
#define BKK 16

enum AMode { A_PLAIN = 0, A_CHARSTATE = 1, A_RH = 2, A_GATHER = 3 };
enum EMode { E_BIAS = 0, E_GATE_CHAR = 1, E_CAND_CHAR = 2, E_XW = 3 };

struct GemmArgs {
  int M, N, K;
  const float* A; int lda;
  const float* G; int ldg;
  const int*   arows;
  const float* B;
  const float* bias;
  const float* XT; int ldxt;
  const int*   seqs;
  const int*   lens;
  int t, T;
  const int*   cidx;
  const float* Hin;
  float* Cout; int ldc;
};

__device__ __forceinline__ float sigmoidf_(float x) { return 1.0f / (1.0f + expf(-x)); }
__device__ __forceinline__ float bf2f_(unsigned short u) {
  return __uint_as_float((unsigned int)u << 16);
}

template<int AM, int EM>
__global__ __launch_bounds__(256) void gemm_k(GemmArgs p) {
  __shared__ float As[BKK][TILE];
  __shared__ float Bs[BKK][TILE];
  const int tid = threadIdx.x;
  const int tx = tid & 15, ty = tid >> 4;
  const int m0 = blockIdx.y * TILE, n0 = blockIdx.x * TILE;
  const int la_r = tid >> 2, la_k = (tid & 3) << 2;
  const int lb_k = tid >> 4, lb_n = (tid & 15) << 2;

  float acc[4][4] = {};
  int arow = 0;
  if constexpr (AM == A_GATHER) arow = p.arows[m0 + la_r];

  for (int k0 = 0; k0 < p.K; k0 += BKK) {
    float4 av;
    const int m = m0 + la_r;
    const int k = k0 + la_k;
    if constexpr (AM == A_PLAIN) {
      av = *reinterpret_cast<const float4*>(p.A + (size_t)m * p.lda + k);
    } else if constexpr (AM == A_CHARSTATE) {
      const float* ap = (k < 512) ? (p.A + (size_t)m * 512 + k)
                                  : (p.A + (size_t)(2048 + m) * 512 + (k - 512));
      av = *reinterpret_cast<const float4*>(ap);
    } else if constexpr (AM == A_RH) {
      float4 g = *reinterpret_cast<const float4*>(p.G + (size_t)m * p.ldg + k);
      float4 h = *reinterpret_cast<const float4*>(p.A + (size_t)m * p.lda + k);
      av = make_float4(g.x * h.x, g.y * h.y, g.z * h.z, g.w * h.w);
    } else { // A_GATHER
      av = *reinterpret_cast<const float4*>(p.A + (size_t)arow * p.lda + k);
    }
    As[la_k + 0][la_r] = av.x;
    As[la_k + 1][la_r] = av.y;
    As[la_k + 2][la_r] = av.z;
    As[la_k + 3][la_r] = av.w;
    float4 bv = *reinterpret_cast<const float4*>(p.B + (size_t)(k0 + lb_k) * p.N + n0 + lb_n);
    *reinterpret_cast<float4*>(&Bs[lb_k][lb_n]) = bv;
    __syncthreads();
#pragma unroll
    for (int kk = 0; kk < BKK; ++kk) {
      float4 a = *reinterpret_cast<const float4*>(&As[kk][ty << 2]);
      float4 b = *reinterpret_cast<const float4*>(&Bs[kk][tx << 2]);
      acc[0][0] += a.x * b.x; acc[0][1] += a.x * b.y; acc[0][2] += a.x * b.z; acc[0][3] += a.x * b.w;
      acc[1][0] += a.y * b.x; acc[1][1] += a.y * b.y; acc[1][2] += a.y * b.z; acc[1][3] += a.y * b.w;
      acc[2][0] += a.z * b.x; acc[2][1] += a.z * b.y; acc[2][2] += a.z * b.z; acc[2][3] += a.z * b.w;
      acc[3][0] += a.w * b.x; acc[3][1] += a.w * b.y; acc[3][2] += a.w * b.z; acc[3][3] += a.w * b.w;
    }
    __syncthreads();
  }

  const int rbase = m0 + (ty << 2);
  const int cbase = n0 + (tx << 2);
#pragma unroll
  for (int i = 0; i < 4; ++i) {
    const int row = rbase + i;
    if constexpr (EM == E_BIAS) {
#pragma unroll
      for (int j = 0; j < 4; ++j) {
        const int col = cbase + j;
        p.Cout[(size_t)row * p.ldc + col] = acc[i][j] + p.bias[col];
      }
    } else if constexpr (EM == E_GATE_CHAR || EM == E_CAND_CHAR) {
      const int us = row & 2047;
      const bool dir = row >= 2048;
      const int len = p.lens[us];
      int pos = dir ? (len - 1 - p.t) : p.t;
      pos = pos < 0 ? 0 : (pos > p.T - 1 ? p.T - 1 : pos);
      const int ch = p.seqs[us * p.T + pos];
      const float* xrow = p.XT + (size_t)ch * p.ldxt;
      const bool mask = p.t < len;
#pragma unroll
      for (int j = 0; j < 4; ++j) {
        const int col = cbase + j;
        if constexpr (EM == E_GATE_CHAR) {
          p.Cout[(size_t)row * p.ldc + col] = sigmoidf_(acc[i][j] + xrow[col]);
        } else {
          const float cv = tanhf(acc[i][j] + xrow[col]);
          const float u  = p.G[(size_t)row * p.ldg + 512 + col];
          const float h  = p.Hin[(size_t)row * 512 + col];
          p.Cout[(size_t)row * p.ldc + col] = mask ? (u * h + (1.0f - u) * cv) : h;
        }
      }
    } else { // E_XW
      const int cs = p.cidx[row];
      const float* xrow = p.XT + (size_t)cs * p.ldxt;
#pragma unroll
      for (int j = 0; j < 4; ++j) {
        const int col = cbase + j;
        p.Cout[(size_t)row * p.ldc + col] = acc[i][j] + xrow[col];
      }
    }
  }
}

// fp32 -> bf16 (RNE) weight conversion
__global__ __launch_bounds__(256) void wconv_k(const float* __restrict__ src,
                                               unsigned short* __restrict__ dst,
                                               int n) {
  const int i = blockIdx.x * 256 + threadIdx.x;
  if (i < n) {
    const unsigned int u = __float_as_uint(src[i]);
    dst[i] = (unsigned short)((u + 0x7FFFu + ((u >> 16) & 1u)) >> 16);
  }
}

// ---------------------------------------------------------------------------
// Fused persistent word GRU, bf16 weights: R=2 rows/block, 256 blocks x 256
// threads. Phase 1: thread owns 4 gate cols (ushort4 weight loads, k-step-4,
// float4 LDS h-reads). Phase 2: thread owns 2 cand cols (ushort2 loads).
// Rows: [0,NU) = forward, [NU,2NU) = backward (dir uniform per block).
// ---------------------------------------------------------------------------
template<int R, int NU, int TT>
__global__ __launch_bounds__(256) void gru_word_bf(
    const unsigned short* __restrict__ Whg,  // [512,1024] bf16
    const unsigned short* __restrict__ Whc,  // [512,512]  bf16
    const float* __restrict__ Xg,            // [NU*TT,1024] (bias folded)
    const float* __restrict__ Xc,            // [NU*TT,512]
    const int*   __restrict__ lens,          // [NU]
    float* __restrict__ Hout)                // [2*NU, 512]
{
  __shared__ float h_s [R][512];
  __shared__ float rh_s[R][512];
  __shared__ float u_s [R][512];
  __shared__ int   xog_s[R];
  __shared__ int   xoc_s[R];
  __shared__ int   msk_s[R];

  const int tid  = threadIdx.x;
  const int row0 = blockIdx.x * R;
  const int us0  = row0 & (NU - 1);
  const bool bw  = row0 >= NU;

  for (int i = tid; i < R * 512; i += 256) h_s[i >> 9][i & 511] = 0.0f;
  int mylen = 0;
  if (tid < R) mylen = lens[us0 + tid];
  __syncthreads();

  const int c0 = tid << 2;   // phase-1: 4 gate cols of 1024
  const int c2 = tid << 1;   // phase-2: 2 cand cols of 512

  for (int t = 0; t < TT; ++t) {
    if (tid < R) {
      int pos = bw ? (mylen - 1 - t) : t;
      pos = pos < 0 ? 0 : (pos > TT - 1 ? TT - 1 : pos);
      const int xr = (us0 + tid) * TT + pos;
      xog_s[tid] = xr * 1024;
      xoc_s[tid] = xr * 512;
      msk_s[tid] = (t < mylen) ? 1 : 0;
    }
    __syncthreads();

    // ---- phase 1: gates = sigmoid(h @ Whg + Xg); rh / u -> LDS ----
    float4 acc[R];
#pragma unroll
    for (int r = 0; r < R; ++r) acc[r] = make_float4(0.f, 0.f, 0.f, 0.f);
#pragma unroll 2
    for (int k0 = 0; k0 < 512; k0 += 4) {
      ushort4 wu[4];
#pragma unroll
      for (int i = 0; i < 4; ++i)
        wu[i] = *reinterpret_cast<const ushort4*>(Whg + (size_t)(k0 + i) * 1024 + c0);
      float4 hv[R];
#pragma unroll
      for (int r = 0; r < R; ++r)
        hv[r] = *reinterpret_cast<const float4*>(&h_s[r][k0]);
#pragma unroll
      for (int i = 0; i < 4; ++i) {
        const float wx = bf2f_(wu[i].x), wy = bf2f_(wu[i].y);
        const float wz = bf2f_(wu[i].z), ww = bf2f_(wu[i].w);
#pragma unroll
        for (int r = 0; r < R; ++r) {
          const float h = (i == 0) ? hv[r].x : (i == 1) ? hv[r].y : (i == 2) ? hv[r].z : hv[r].w;
          acc[r].x += h * wx; acc[r].y += h * wy;
          acc[r].z += h * wz; acc[r].w += h * ww;
        }
      }
    }
#pragma unroll
    for (int r = 0; r < R; ++r) {
      const float4 x = *reinterpret_cast<const float4*>(Xg + xog_s[r] + c0);
      float4 g;
      g.x = sigmoidf_(acc[r].x + x.x);
      g.y = sigmoidf_(acc[r].y + x.y);
      g.z = sigmoidf_(acc[r].z + x.z);
      g.w = sigmoidf_(acc[r].w + x.w);
      if (c0 < 512) {        // r-gate cols -> rh = r * h
        const float4 hh = *reinterpret_cast<const float4*>(&h_s[r][c0]);
        rh_s[r][c0 + 0] = g.x * hh.x;
        rh_s[r][c0 + 1] = g.y * hh.y;
        rh_s[r][c0 + 2] = g.z * hh.z;
        rh_s[r][c0 + 3] = g.w * hh.w;
      } else {               // u-gate cols
        u_s[r][c0 - 512 + 0] = g.x;
        u_s[r][c0 - 512 + 1] = g.y;
        u_s[r][c0 - 512 + 2] = g.z;
        u_s[r][c0 - 512 + 3] = g.w;
      }
    }
    __syncthreads();

    // ---- phase 2: c = tanh(rh @ Whc + Xc); h' = mask ? u*h+(1-u)*c : h ----
    float2 acc2[R];
#pragma unroll
    for (int r = 0; r < R; ++r) acc2[r] = make_float2(0.f, 0.f);
#pragma unroll 2
    for (int k0 = 0; k0 < 512; k0 += 4) {
      ushort2 wu[4];
#pragma unroll
      for (int i = 0; i < 4; ++i)
        wu[i] = *reinterpret_cast<const ushort2*>(Whc + (size_t)(k0 + i) * 512 + c2);
      float4 rv[R];
#pragma unroll
      for (int r = 0; r < R; ++r)
        rv[r] = *reinterpret_cast<const float4*>(&rh_s[r][k0]);
#pragma unroll
      for (int i = 0; i < 4; ++i) {
        const float wx = bf2f_(wu[i].x), wy = bf2f_(wu[i].y);
#pragma unroll
        for (int r = 0; r < R; ++r) {
          const float rvv = (i == 0) ? rv[r].x : (i == 1) ? rv[r].y : (i == 2) ? rv[r].z : rv[r].w;
          acc2[r].x += rvv * wx; acc2[r].y += rvv * wy;
        }
      }
    }
#pragma unroll
    for (int r = 0; r < R; ++r) {
      const float2 x = *reinterpret_cast<const float2*>(Xc + xoc_s[r] + c2);
      const float cx = tanhf(acc2[r].x + x.x);
      const float cy = tanhf(acc2[r].y + x.y);
      if (msk_s[r]) {
        const float ux = u_s[r][c2], uy = u_s[r][c2 + 1];
        const float hx = h_s[r][c2], hy = h_s[r][c2 + 1];
        h_s[r][c2]     = ux * hx + (1.0f - ux) * cx;
        h_s[r][c2 + 1] = uy * hy + (1.0f - uy) * cy;
      }
    }
    __syncthreads();
  }

  for (int i = tid; i < R * 512; i += 256)
    Hout[(size_t)(row0 + (i >> 9)) * 512 + (i & 511)] = h_s[i >> 9][i & 511];
}

// FC head
__global__ __launch_bounds__(64) void head_k(const float* __restrict__ Hw,
                                             const float* __restrict__ W1,
                                             const float* __restrict__ b1,
                                             const float* __restrict__ W2,
                                             const float* __restrict__ b2,
                                             float* __restrict__ out) {
  __shared__ float s[1024];
  __shared__ float hid[64];
  const int b = blockIdx.x;
  const int tid = threadIdx.x;
  for (int k = tid; k < 512; k += 64) {
    s[k]       = Hw[(size_t)b * 512 + k];
    s[512 + k] = Hw[(size_t)(256 + b) * 512 + k];
  }
  __syncthreads();
  float acc = b1[tid];
  for (int k = 0; k < 1024; ++k) acc += s[k] * W1[k * 64 + tid];
  acc = acc > 0.0f ? acc : 0.2f * acc;
  hid[tid] = acc;
  __syncthreads();
  if (tid < 2) {
    float a = b2[tid];
    for (int k = 0; k < 64; ++k) a += hid[k] * W2[k * 2 + tid];
    out[b * 2 + tid] = a;
  }
}

extern "C" void kernel_launch(void* const* d_in, const int* in_sizes, int n_in,
                              void* d_out, int out_size, void* d_ws, size_t ws_size,
                              hipStream_t stream) {
  const int*   charseqs      = (const int*)d_in[0];
  const int*   charseq_lens  = (const int*)d_in[1];
  const int*   charseq_ids   = (const int*)d_in[2];
  const int*   word_ids      = (const int*)d_in[3];
  const int*   sentence_lens = (const int*)d_in[4];
  const float* char_emb      = (const float*)d_in[5];
  const float* word_emb      = (const float*)d_in[6];
  const float* Wg_c          = (const float*)d_in[7];
  const float* bg_c          = (const float*)d_in[8];
  const float* Wc_c          = (const float*)d_in[9];
  const float* bc_c          = (const float*)d_in[10];
  const float* Wg_w          = (const float*)d_in[11];
  const float* bg_w          = (const float*)d_in[12];
  const float* Wc_w          = (const float*)d_in[13];
  const float* bc_w          = (const float*)d_in[14];
  const float* W1            = (const float*)d_in[15];
  const float* b1            = (const float*)d_in[16];
  const float* W2            = (const float*)d_in[17];
  const float* b2            = (const float*)d_in[18];
  float* out = (float*)d_out;

  float* ws = (float*)d_ws;
  size_t off = 0;
  auto alloc = [&](size_t n) { float* p = ws + off; off += n; return p; };
  float* XTABg = alloc(256 * 1024);
  float* XTABc = alloc(256 * 512);
  float* HcA   = alloc((size_t)4096 * 512);
  float* HcB   = alloc((size_t)4096 * 512);
  float* Gc    = alloc((size_t)4096 * 1024);
  float* CTABg = alloc((size_t)2048 * 1024);
  float* CTABc = alloc((size_t)2048 * 512);
  float* XWg   = alloc((size_t)16384 * 1024);
  float* XWc   = alloc((size_t)16384 * 512);
  float* Hw    = alloc(512 * 512);
  unsigned short* WhgBF = (unsigned short*)alloc(512 * 1024 / 2); // 512K bf16
  unsigned short* WhcBF = (unsigned short*)alloc(512 * 512 / 2);  // 256K bf16

  hipMemsetAsync(HcA, 0, (size_t)4096 * 512 * sizeof(float), stream);

  // --- Stage 0: convert word recurrent weights to bf16 (RNE) ---
  wconv_k<<<(512 * 1024 + 255) / 256, 256, 0, stream>>>(
      Wg_w + (size_t)1280 * 1024, WhgBF, 512 * 1024);
  wconv_k<<<(512 * 512 + 255) / 256, 256, 0, stream>>>(
      Wc_w + (size_t)1280 * 512, WhcBF, 512 * 512);

  // --- Stage A: char x-part tables ---
  {
    GemmArgs a{}; a.M = 256; a.N = 1024; a.K = 128;
    a.A = char_emb; a.lda = 128; a.B = Wg_c; a.bias = bg_c; a.Cout = XTABg; a.ldc = 1024;
    gemm_k<A_PLAIN, E_BIAS><<<dim3(1024 / TILE, 256 / TILE), 256, 0, stream>>>(a);
    GemmArgs c{}; c.M = 256; c.N = 512; c.K = 128;
    c.A = char_emb; c.lda = 128; c.B = Wc_c; c.bias = bc_c; c.Cout = XTABc; c.ldc = 512;
    gemm_k<A_PLAIN, E_BIAS><<<dim3(512 / TILE, 256 / TILE), 256, 0, stream>>>(c);
  }

  // --- Stage B: char bi-GRU GEMM loop (64-tile, r8 config, fp32) ---
  float* hcur = HcA; float* hnext = HcB;
  for (int t = 0; t < 16; ++t) {
    GemmArgs g{}; g.M = 4096; g.N = 1024; g.K = 512;
    g.A = hcur; g.lda = 512; g.B = Wg_c + 128 * 1024;
    g.XT = XTABg; g.ldxt = 1024; g.seqs = charseqs; g.lens = charseq_lens; g.t = t; g.T = 16;
    g.Cout = Gc; g.ldc = 1024;
    gemm_k<A_PLAIN, E_GATE_CHAR><<<dim3(1024 / TILE, 4096 / TILE), 256, 0, stream>>>(g);

    GemmArgs c{}; c.M = 4096; c.N = 512; c.K = 512;
    c.A = hcur; c.lda = 512; c.G = Gc; c.ldg = 1024; c.B = Wc_c + 128 * 512;
    c.XT = XTABc; c.ldxt = 512; c.seqs = charseqs; c.lens = charseq_lens; c.t = t; c.T = 16;
    c.Hin = hcur; c.Cout = hnext; c.ldc = 512;
    gemm_k<A_RH, E_CAND_CHAR><<<dim3(512 / TILE, 4096 / TILE), 256, 0, stream>>>(c);

    float* tmp = hcur; hcur = hnext; hnext = tmp;
  }
  // after 16 steps hcur == HcA

  // --- Stage C: per-wordform x-part ---
  {
    GemmArgs a{}; a.M = 2048; a.N = 1024; a.K = 1024;
    a.A = hcur; a.B = Wg_w; a.bias = bg_w; a.Cout = CTABg; a.ldc = 1024;
    gemm_k<A_CHARSTATE, E_BIAS><<<dim3(1024 / TILE, 2048 / TILE), 256, 0, stream>>>(a);
    GemmArgs c{}; c.M = 2048; c.N = 512; c.K = 1024;
    c.A = hcur; c.B = Wc_w; c.bias = bc_w; c.Cout = CTABc; c.ldc = 512;
    gemm_k<A_CHARSTATE, E_BIAS><<<dim3(512 / TILE, 2048 / TILE), 256, 0, stream>>>(c);
  }

  // --- Stage D: word-emb x-part + CTAB gather ---
  {
    GemmArgs a{}; a.M = 16384; a.N = 1024; a.K = 256;
    a.A = word_emb; a.lda = 256; a.arows = word_ids; a.B = Wg_w + (size_t)1024 * 1024;
    a.XT = CTABg; a.ldxt = 1024; a.cidx = charseq_ids; a.Cout = XWg; a.ldc = 1024;
    gemm_k<A_GATHER, E_XW><<<dim3(1024 / TILE, 16384 / TILE), 256, 0, stream>>>(a);
    GemmArgs c{}; c.M = 16384; c.N = 512; c.K = 256;
    c.A = word_emb; c.lda = 256; c.arows = word_ids; c.B = Wc_w + (size_t)1024 * 512;
    c.XT = CTABc; c.ldxt = 512; c.cidx = charseq_ids; c.Cout = XWc; c.ldc = 512;
    gemm_k<A_GATHER, E_XW><<<dim3(512 / TILE, 16384 / TILE), 256, 0, stream>>>(c);
  }

  // --- Stage E: fused word bi-GRU, bf16 weights (R=2, 256 blocks x 256 thr) ---
  gru_word_bf<2, 256, 64><<<256, 256, 0, stream>>>(
      WhgBF, WhcBF, XWg, XWc, sentence_lens, Hw);

  // --- Stage F: FC head ---
  head_k<<<256, 64, 0, stream>>>(Hw, W1, b1, W2, b2, out);
}